// Round 8
// baseline (193.701 us; speedup 1.0000x reference)
//
#include <hip/hip_runtime.h>
#include <math.h>

namespace {

constexpr int B_ = 8, C_ = 256, H_ = 128, W_ = 192;
constexpr int HW = H_ * W_;
constexpr int TH = 4;                 // h rows per block
constexpr int TW = 32;                // w cols per block (2 m-tiles)
constexpr int NTHREADS = 576;         // 9 waves, wave = dy
constexpr int KCH = 32;               // channels per k-chunk (one MFMA K)
constexpr int NCHUNK = C_ / KCH;      // 8
constexpr int BROWS = 12;             // staged f2 rows  (h0-4 .. h0+7)
constexpr int BPOS = 48;              // staged f2 cols  (w0-4 .. w0+43), 3 tiles
constexpr int POSB = 80;              // bytes per pos: 32ch*2B + 16 pad (odd slots)
constexpr int TILEB = 16 * POSB;      // 1280 B per 16-pos fragment tile
constexpr int ATILES = TH * 2;        // 8
constexpr int BTILES = BROWS * 3;     // 36
constexpr int BUFB = (ATILES + BTILES) * TILEB;   // 56320 B, SINGLE buffer
// epilogue overlay (dead after last compute + barrier):
constexpr int OSTR = 144;             // out-LDS row stride bytes (36 f32)
constexpr int NP1OFF = 46720;         // 512 f32 f1-norm partials
constexpr int INV1OFF = 48768;        // 128 f32
constexpr int INV2OFF = 49280;        // 576 f32

typedef _Float16 f16x8 __attribute__((ext_vector_type(8)));
typedef float f32x4 __attribute__((ext_vector_type(4)));
typedef _Float16 h2 __attribute__((ext_vector_type(2)));

__device__ __forceinline__ unsigned pk2(float x, float y) {
    return __builtin_bit_cast(unsigned, __builtin_amdgcn_cvt_pkrtz(x, y));
}
__device__ __forceinline__ float dot2f(unsigned a, unsigned b, float c) {
#if __has_builtin(__builtin_amdgcn_fdot2)
    return __builtin_amdgcn_fdot2(__builtin_bit_cast(h2, a),
                                  __builtin_bit_cast(h2, b), c, false);
#else
    const h2 ha = __builtin_bit_cast(h2, a), hb = __builtin_bit_cast(h2, b);
    return fmaf((float)ha.x, (float)hb.x, fmaf((float)ha.y, (float)hb.y, c));
#endif
}

__global__ __launch_bounds__(NTHREADS, 2)
void local_corr_mfma(const float* __restrict__ f1g,
                     const float* __restrict__ f2g,
                     float* __restrict__ outg)
{
    __shared__ __align__(16) char lds[BUFB];   // 56320 B -> 2 blocks/CU

    // XCD swizzle: batch image == XCD id; within XCD w-major for f2 row reuse
    const int m  = blockIdx.x;            // 0..1535
    const int b  = m & 7;
    const int k  = m >> 3;                // 0..191
    const int bx = k % 6;
    const int by = k / 6;                 // 0..31
    const int w0 = bx * TW, h0 = by * TH;

    const int tid  = threadIdx.x;
    const int dyi  = tid >> 6;            // wave = dy 0..8
    const int lane = tid & 63;
    const int lp   = lane & 15;           // fragment pos index (m or n)
    const int lg   = lane >> 4;           // k-group

    // ---- B staging: thread owns f2 pos tid (all 4 ch-octets) ----
    const int brow = tid / BPOS, bpc = tid % BPOS;   // 12 x 48 = 576
    const int bgh = h0 - 4 + brow, bgw = w0 - 4 + bpc;
    const bool bok = (bgh >= 0) && (bgh < H_) && (bgw >= 0) && (bgw < W_);
    const int bghc = bgh < 0 ? 0 : (bgh >= H_ ? H_ - 1 : bgh);
    const int bgwc = bgw < 0 ? 0 : (bgw >= W_ ? W_ - 1 : bgw);
    const int bwoff = (ATILES + brow * 3 + bpc / 16) * TILEB + (bpc % 16) * POSB;

    // ---- A staging: threads < 512, one ch-octet of f1 pos (t&127) ----
    const bool hasA = tid < 512;
    const int aoct = tid >> 7, apos = tid & 127;
    const int ah = apos >> 5, aw = apos & 31;
    const int awoff = (ah * 2 + aw / 16) * TILEB + (aw % 16) * POSB + aoct * 16;

    // running per-chunk pointers (advance by KCH*HW per chunk)
    const float* bptr = f2g + (size_t)b * C_ * HW + (size_t)bghc * W_ + bgwc;
    const float* aptr = f1g + (size_t)b * C_ * HW + (size_t)(h0 + ah) * W_ + (w0 + aw)
                            + (size_t)(8 * aoct) * HW;

    float bv[4][8], av[8];
    float bn = 0.f, an = 0.f;             // f16-value squared norms

    auto issueLoads = [&]() {
#pragma unroll
        for (int o = 0; o < 4; ++o)
#pragma unroll
            for (int j = 0; j < 8; ++j)
                bv[o][j] = bptr[(size_t)(8 * o + j) * HW];
        if (hasA)
#pragma unroll
            for (int j = 0; j < 8; ++j)
                av[j] = aptr[(size_t)j * HW];
        bptr += (size_t)KCH * HW;
        aptr += (size_t)KCH * HW;
    };

    auto writeStage = [&]() {
#pragma unroll
        for (int o = 0; o < 4; ++o) {
            unsigned u[4];
#pragma unroll
            for (int q = 0; q < 4; ++q) {
                const float x = bok ? bv[o][2 * q] : 0.f;
                const float y = bok ? bv[o][2 * q + 1] : 0.f;
                u[q] = pk2(x, y);
                bn = dot2f(u[q], u[q], bn);
            }
            *reinterpret_cast<uint4*>(lds + bwoff + o * 16) =
                make_uint4(u[0], u[1], u[2], u[3]);
        }
        if (hasA) {
            unsigned u[4];
#pragma unroll
            for (int q = 0; q < 4; ++q) {
                u[q] = pk2(av[2 * q], av[2 * q + 1]);
                an = dot2f(u[q], u[q], an);
            }
            *reinterpret_cast<uint4*>(lds + awoff) = make_uint4(u[0], u[1], u[2], u[3]);
        }
    };

    f32x4 acc[TH][4];                     // [h][mt0bt0, mt0bt1, mt1bt1, mt1bt2]
#pragma unroll
    for (int h = 0; h < TH; ++h)
#pragma unroll
        for (int j = 0; j < 4; ++j) acc[h][j] = (f32x4)0.f;

    const int fro = lp * POSB + lg * 16;  // fragment read offset within tile

    auto computeChunk = [&]() {
#pragma unroll
        for (int h = 0; h < TH; ++h) {
            const char* at = lds + (h * 2) * TILEB;
            const f16x8 fa0 = *reinterpret_cast<const f16x8*>(at + fro);
            const f16x8 fa1 = *reinterpret_cast<const f16x8*>(at + TILEB + fro);
            const char* bt = lds + (ATILES + (h + dyi) * 3) * TILEB;
            const f16x8 fb0 = *reinterpret_cast<const f16x8*>(bt + fro);
            const f16x8 fb1 = *reinterpret_cast<const f16x8*>(bt + TILEB + fro);
            const f16x8 fb2 = *reinterpret_cast<const f16x8*>(bt + 2 * TILEB + fro);
            acc[h][0] = __builtin_amdgcn_mfma_f32_16x16x32_f16(fa0, fb0, acc[h][0], 0, 0, 0);
            acc[h][1] = __builtin_amdgcn_mfma_f32_16x16x32_f16(fa0, fb1, acc[h][1], 0, 0, 0);
            acc[h][2] = __builtin_amdgcn_mfma_f32_16x16x32_f16(fa1, fb1, acc[h][2], 0, 0, 0);
            acc[h][3] = __builtin_amdgcn_mfma_f32_16x16x32_f16(fa1, fb2, acc[h][3], 0, 0, 0);
        }
    };

    // ---- pipelined K loop, single LDS buffer, reg-buffered in-flight loads ----
    issueLoads();
    writeStage();
    __syncthreads();
    for (int t = 0; t < NCHUNK; ++t) {
        const bool more = (t + 1) < NCHUNK;
        if (more) issueLoads();           // in flight during compute(t)
        computeChunk();
        __syncthreads();                  // all reads of buffer done
        if (more) writeStage();           // vmcnt wait lands here
        __syncthreads();                  // buffer ready for t+1
    }

    // ---- norms -> inv arrays (buffer now dead -> overlay epilogue) ----
    float* nf1p = reinterpret_cast<float*>(lds + NP1OFF);
    float* inv2 = reinterpret_cast<float*>(lds + INV2OFF);
    if (hasA) nf1p[aoct * 128 + apos] = an;
    inv2[tid] = 1.0f / fmaxf(sqrtf(bn), 1e-12f);
    __syncthreads();
    float* inv1 = reinterpret_cast<float*>(lds + INV1OFF);
    if (tid < 128) {
        const float s = nf1p[tid] + nf1p[128 + tid] + nf1p[256 + tid] + nf1p[384 + tid];
        inv1[tid] = 1.0f / fmaxf(sqrtf(s), 1e-12f);    // index = ah*32 + aw
    }
    __syncthreads();

    // ---- normalize + band-masked transpose into out-LDS [81][TH][32] ----
#pragma unroll
    for (int h = 0; h < TH; ++h) {
#pragma unroll
        for (int j = 0; j < 4; ++j) {
            const int mt = j >> 1, bt = mt + (j & 1);
            const float v2 = inv2[(h + dyi) * BPOS + bt * 16 + lp];   // n = lp
#pragma unroll
            for (int r = 0; r < 4; ++r) {
                const int mloc = 4 * lg + r;
                const int band = lp - mloc + ((j & 1) ? 16 : 0);      // dx+4
                if (band >= 0 && band <= 8) {
                    const float v1 = inv1[h * 32 + mt * 16 + mloc];
                    const int od = dyi * 9 + band;
                    float* orow = reinterpret_cast<float*>(lds + (od * TH + h) * OSTR);
                    orow[mt * 16 + mloc] = acc[h][j][r] * v1 * v2;
                }
            }
        }
    }
    __syncthreads();

    // ---- coalesced store: 81*4*8 = 2592 float4 quads ----
    const size_t obase = (size_t)b * 81 * HW;
    for (int s = tid; s < 81 * TH * 8; s += NTHREADS) {
        const int od = s >> 5;            // 32 quads per od
        const int rem = s & 31;
        const int h = rem >> 3, q = rem & 7;
        const float4 v = *reinterpret_cast<const float4*>(lds + (od * TH + h) * OSTR + q * 16);
        *reinterpret_cast<float4*>(outg + obase + (size_t)od * HW +
                                   (size_t)(h0 + h) * W_ + w0 + q * 4) = v;
    }
}

} // namespace

extern "C" void kernel_launch(void* const* d_in, const int* in_sizes, int n_in,
                              void* d_out, int out_size, void* d_ws, size_t ws_size,
                              hipStream_t stream)
{
    (void)in_sizes; (void)n_in; (void)d_ws; (void)ws_size; (void)out_size;
    const float* f1 = (const float*)d_in[0];
    const float* f2 = (const float*)d_in[1];
    float* out = (float*)d_out;

    dim3 grid(1536, 1, 1);     // 8b x 32hb x 6wb, XCD-chunked inside kernel
    dim3 block(NTHREADS);      // 576 threads = 9 waves (wave = dy)
    local_corr_mfma<<<grid, block, 0, stream>>>(f1, f2, out);
}

// Round 9
// 172.663 us; speedup vs baseline: 1.1218x; 1.1218x over previous
//
#include <hip/hip_runtime.h>
#include <math.h>

namespace {

constexpr int B_ = 8, C_ = 256, H_ = 128, W_ = 192;
constexpr int HW = H_ * W_;
constexpr size_t CHW = (size_t)C_ * HW;
constexpr int TH = 8, TW = 16;          // block tile
constexpr int NTHREADS = 512;           // 8 waves, wave = h row
constexpr int KCH = 16;                 // channels per chunk
constexpr int NCHUNK = C_ / KCH;        // 16
constexpr int BROWS = 16;               // staged f2 rows h0-4 .. h0+11
constexpr int BPOS = 32;                // staged f2 cols w0-8 .. w0+23 (2 tiles)
constexpr int POSB = 48;                // 32B data + 16B pad (3 slots, odd -> bank-uniform)
constexpr int ROWB = BPOS * POSB;       // 1536
constexpr int BUFB = BROWS * ROWB;      // 24576 B (single buffer)
constexpr int OSTR = 20;                // out-LDS dwords/row; 4 rows/od: 4*20%32=16 != 0
constexpr int OUTB = 81 * 4 * OSTR * 4; // 25920 (one h-half)
constexpr int BNOFF = OUTB;             // f2 norms [16][32] f32
constexpr int LDSB = BNOFF + BROWS * BPOS * 4;  // 27968

typedef _Float16 f16x4 __attribute__((ext_vector_type(4)));
typedef _Float16 f16x8 __attribute__((ext_vector_type(8)));
typedef float f32x4 __attribute__((ext_vector_type(4)));
typedef _Float16 h2 __attribute__((ext_vector_type(2)));

__device__ __forceinline__ unsigned pk2(float x, float y) {
    return __builtin_bit_cast(unsigned, __builtin_amdgcn_cvt_pkrtz(x, y));
}
__device__ __forceinline__ float dot2f(unsigned a, unsigned b, float c) {
#if __has_builtin(__builtin_amdgcn_fdot2)
    return __builtin_amdgcn_fdot2(__builtin_bit_cast(h2, a),
                                  __builtin_bit_cast(h2, b), c, false);
#else
    const h2 ha = __builtin_bit_cast(h2, a), hb = __builtin_bit_cast(h2, b);
    return fmaf((float)ha.x, (float)hb.x, fmaf((float)ha.y, (float)hb.y, c));
#endif
}
__device__ __forceinline__ f32x4 mfma16(f16x4 a, f16x4 b, f32x4 c) {
#if __has_builtin(__builtin_amdgcn_mfma_f32_16x16x16f16)
    return __builtin_amdgcn_mfma_f32_16x16x16f16(a, b, c, 0, 0, 0);
#else
    // zero-padded K=32 fallback: identical k-placement for A and B -> same dot
    const f16x8 a8 = {a[0], a[1], a[2], a[3], (_Float16)0, (_Float16)0, (_Float16)0, (_Float16)0};
    const f16x8 b8 = {b[0], b[1], b[2], b[3], (_Float16)0, (_Float16)0, (_Float16)0, (_Float16)0};
    return __builtin_amdgcn_mfma_f32_16x16x32_f16(a8, b8, c, 0, 0, 0);
#endif
}

__global__ __launch_bounds__(NTHREADS)
void local_corr_mfma(const float* __restrict__ f1g,
                     const float* __restrict__ f2g,
                     float* __restrict__ outg)
{
    __shared__ __align__(16) char lds[LDSB];

    // XCD swizzle: image = XCD id; w-major within image for L2 stripe reuse
    const int m  = blockIdx.x;          // 0..1535
    const int b  = m & 7;
    const int k  = m >> 3;              // 0..191
    const int bx = k % 12;
    const int by = k / 12;              // 0..15
    const int w0 = bx * TW, h0 = by * TH;

    const int tid  = threadIdx.x;
    const int hs   = tid >> 6;          // wave = h row 0..7
    const int lane = tid & 63;
    const int lp   = lane & 15;         // fragment pos
    const int lg   = lane >> 4;         // k-group (ch 4*lg..4*lg+3)

    // ---- B staging: thread owns one staged f2 position (sr, sc) ----
    const int sr = tid >> 5;            // 0..15
    const int sc = tid & 31;            // 0..31
    const int bgh = h0 - 4 + sr, bgw = w0 - 8 + sc;
    const bool bok = (bgh >= 0) && (bgh < H_) && (bgw >= 0) && (bgw < W_);
    const int bghc = min(max(bgh, 0), H_ - 1);
    const int bgwc = min(max(bgw, 0), W_ - 1);
    const float* bptr = f2g + (size_t)b * CHW + (size_t)bghc * W_ + bgwc;
    // ---- A direct-from-global: lane (lp,lg) owns f1[h0+hs][w0+lp], ch 4lg+j ----
    const float* aptr = f1g + (size_t)b * CHW + (size_t)(h0 + hs) * W_ + (w0 + lp)
                            + (size_t)(4 * lg) * HW;

    float bvr[16], avr[4];
    float bn = 0.f, an = 0.f;
    f16x4 afrag;

    auto issue = [&]() {
#pragma unroll
        for (int j = 0; j < 16; ++j) bvr[j] = bptr[(size_t)j * HW];
#pragma unroll
        for (int j = 0; j < 4; ++j) avr[j] = aptr[(size_t)j * HW];
        bptr += (size_t)KCH * HW;
        aptr += (size_t)KCH * HW;
    };

    auto stage = [&]() {
        unsigned u[8];
#pragma unroll
        for (int q = 0; q < 8; ++q) {
            const float x = bok ? bvr[2 * q] : 0.f;
            const float y = bok ? bvr[2 * q + 1] : 0.f;
            u[q] = pk2(x, y);
            bn = dot2f(u[q], u[q], bn);
        }
        char* dst = lds + tid * POSB;
        *reinterpret_cast<uint4*>(dst)      = make_uint4(u[0], u[1], u[2], u[3]);
        *reinterpret_cast<uint4*>(dst + 16) = make_uint4(u[4], u[5], u[6], u[7]);
        const unsigned a0 = pk2(avr[0], avr[1]);
        const unsigned a1 = pk2(avr[2], avr[3]);
        an = dot2f(a0, a0, an);
        an = dot2f(a1, a1, an);
        afrag = __builtin_bit_cast(f16x4, make_uint2(a0, a1));
    };

    f32x4 acc[9][2];
#pragma unroll
    for (int dy = 0; dy < 9; ++dy)
#pragma unroll
        for (int bt = 0; bt < 2; ++bt) acc[dy][bt] = (f32x4)0.f;

    const int fro = lp * POSB + lg * 8;

    auto compute = [&]() {
#pragma unroll
        for (int dy = 0; dy < 9; ++dy) {
            const char* rbase = lds + (hs + dy) * ROWB + fro;
            const f16x4 b0 = *reinterpret_cast<const f16x4*>(rbase);
            const f16x4 b1 = *reinterpret_cast<const f16x4*>(rbase + 16 * POSB);
            acc[dy][0] = mfma16(afrag, b0, acc[dy][0]);
            acc[dy][1] = mfma16(afrag, b1, acc[dy][1]);
        }
    };

    // ---- pipelined K loop: issue(t+1) | compute(t) | barrier | stage(t+1) | barrier
    issue();
    stage();
    __syncthreads();
    for (int t = 0; t < NCHUNK; ++t) {
        const bool more = (t + 1) < NCHUNK;
        if (more) issue();
        compute();
        __syncthreads();
        if (more) stage();
        __syncthreads();
    }

    // ---- norms ----
    float* bnorm = reinterpret_cast<float*>(lds + BNOFF);   // [16][32]
    bnorm[tid] = bn;
    an += __shfl_xor(an, 16);
    an += __shfl_xor(an, 32);                               // full norm of pos lp
    const float inv1own = 1.0f / fmaxf(sqrtf(an), 1e-12f);
    __syncthreads();

    // ---- epilogue: two h-half passes through 26 KB out-LDS ----
    const size_t obase = (size_t)b * 81 * HW;
#pragma unroll
    for (int pass = 0; pass < 2; ++pass) {
        if ((hs >> 2) == pass) {
            const int h4 = hs & 3;
#pragma unroll
            for (int dy = 0; dy < 9; ++dy) {
#pragma unroll
                for (int bt = 0; bt < 2; ++bt) {
                    const int scol = bt * 16 + lp;                 // staged f2 col
                    const float nb = bnorm[(hs + dy) * 32 + scol];
                    const float v2 = 1.0f / fmaxf(sqrtf(nb), 1e-12f);
#pragma unroll
                    for (int r = 0; r < 4; ++r) {
                        const int mw  = 4 * lg + r;                // f1 w within tile
                        const int dxi = scol - 4 - mw;             // dx + 4
                        const float v1 = __shfl(inv1own, mw);
                        if (dxi >= 0 && dxi <= 8) {
                            float* orow = reinterpret_cast<float*>(lds)
                                        + ((dy * 9 + dxi) * 4 + h4) * OSTR;
                            orow[mw] = acc[dy][bt][r] * v1 * v2;
                        }
                    }
                }
            }
        }
        __syncthreads();
        for (int s = tid; s < 81 * 4 * 4; s += NTHREADS) {
            const int od = s >> 4;
            const int rem = s & 15;
            const int h4 = rem >> 2, q = rem & 3;
            const float4 v = *reinterpret_cast<const float4*>(
                reinterpret_cast<const float*>(lds) + (od * 4 + h4) * OSTR + q * 4);
            *reinterpret_cast<float4*>(outg + obase + (size_t)od * HW +
                                       (size_t)(h0 + pass * 4 + h4) * W_ + w0 + q * 4) = v;
        }
        if (pass == 0) __syncthreads();
    }
}

} // namespace

extern "C" void kernel_launch(void* const* d_in, const int* in_sizes, int n_in,
                              void* d_out, int out_size, void* d_ws, size_t ws_size,
                              hipStream_t stream)
{
    (void)in_sizes; (void)n_in; (void)d_ws; (void)ws_size; (void)out_size;
    const float* f1 = (const float*)d_in[0];
    const float* f2 = (const float*)d_in[1];
    float* out = (float*)d_out;

    dim3 grid(1536, 1, 1);     // 8 images x 16 hb x 12 wb, XCD-chunked in kernel
    dim3 block(NTHREADS);      // 512 threads = 8 waves (wave = h row)
    local_corr_mfma<<<grid, block, 0, stream>>>(f1, f2, out);
}